// Round 1
// baseline (30435.941 us; speedup 1.0000x reference)
//
#include <hip/hip_runtime.h>
#include <hip/hip_bf16.h>
#include <math.h>

// Problem constants (GPT forward, fp32)
#define L   12
#define D   726
#define H   16
#define HD  45
#define TT  258
#define BB  16
#define VV  50257
#define FFD 2904          // 4*D
#define MTOK (BB*TT)      // 4128 token rows
#define HHD  (H*HD)       // 720

// ---------------- embedding: x = tok_emb[idx] + pos_emb[t] ----------------
__global__ void embed_kernel(const int* __restrict__ idx, const float* __restrict__ tok,
                             const float* __restrict__ pos, float* __restrict__ x) {
  int row = blockIdx.x;            // b*TT + t
  int t = row % TT;
  int token = idx[row];
  const float* te = tok + (size_t)token * D;
  const float* pe = pos + (size_t)t * D;
  float* xr = x + (size_t)row * D;
  for (int d = threadIdx.x; d < D; d += blockDim.x)
    xr[d] = te[d] + pe[d];
}

// ---------------- block-wide sum (256 threads = 4 waves) ----------------
__inline__ __device__ float blk_sum(float v, float* sm) {
  #pragma unroll
  for (int off = 32; off; off >>= 1) v += __shfl_down(v, off);
  int lane = threadIdx.x & 63, w = threadIdx.x >> 6;
  if (lane == 0) sm[w] = v;
  __syncthreads();
  float r = sm[0] + sm[1] + sm[2] + sm[3];
  __syncthreads();
  return r;
}

// ---------------- layernorm: out = (x-mean)*rsqrt(var+eps)*g + b ----------------
__global__ void ln_kernel(const float* __restrict__ x, const float* __restrict__ g,
                          const float* __restrict__ b, float* __restrict__ out) {
  __shared__ float sm[4];
  int row = blockIdx.x;
  const float* xr = x + (size_t)row * D;
  float s = 0.f;
  for (int i = threadIdx.x; i < D; i += 256) s += xr[i];
  float mean = blk_sum(s, sm) * (1.0f / D);
  float vs = 0.f;
  for (int i = threadIdx.x; i < D; i += 256) { float d0 = xr[i] - mean; vs += d0 * d0; }
  float var = blk_sum(vs, sm) * (1.0f / D);
  float inv = rsqrtf(var + 1e-5f);
  float* orow = out + (size_t)row * D;
  for (int i = threadIdx.x; i < D; i += 256)
    orow[i] = (xr[i] - mean) * inv * g[i] + b[i];
}

// ---------------- repack Wq/Wk/Wv layer slice [H][D][HD] -> [D][H*HD] ----------------
__global__ void repack_kernel(const float* __restrict__ W, float* __restrict__ Bm) {
  int i = blockIdx.x * 256 + threadIdx.x;
  if (i >= D * HHD) return;
  int d = i / HHD, n = i % HHD;
  int h = n / HD, kk = n % HD;
  Bm[i] = W[((size_t)h * D + d) * HD + kk];
}

// ---------------- generic fp32 GEMM: C = [resid +] relu?(A*B + bias) ----------------
// A [M,K] row-major, B [K,N] row-major. 64x64 tile, BK=16, 256 thr, 4x4 microtile.
__global__ __launch_bounds__(256) void gemm_kernel(
    const float* __restrict__ A, const float* __restrict__ Bm,
    const float* __restrict__ bias, const float* __restrict__ resid,
    float* __restrict__ C, int M, int N, int K, int do_relu) {
  __shared__ float As[16][68];   // [kk][m], stride 68 floats => rows 16B-aligned
  __shared__ float Bs[16][68];   // [kk][n]
  int tid = threadIdx.x;
  int tx = tid & 15, ty = tid >> 4;
  int bm = blockIdx.y * 64, bn = blockIdx.x * 64;
  float acc[4][4] = {};
  for (int k0 = 0; k0 < K; k0 += 16) {
    #pragma unroll
    for (int e = 0; e < 4; e++) {
      int lin = tid + e * 256;
      int m = lin >> 4, kk = lin & 15;          // A tile: 64 rows x 16 k
      float va = 0.f;
      if (bm + m < M && k0 + kk < K) va = A[(size_t)(bm + m) * K + k0 + kk];
      As[kk][m] = va;
      int kk2 = lin >> 6, n = lin & 63;         // B tile: 16 k x 64 cols
      float vb = 0.f;
      if (k0 + kk2 < K && bn + n < N) vb = Bm[(size_t)(k0 + kk2) * N + bn + n];
      Bs[kk2][n] = vb;
    }
    __syncthreads();
    #pragma unroll
    for (int kk = 0; kk < 16; kk++) {
      float a[4], bb[4];
      #pragma unroll
      for (int i = 0; i < 4; i++) a[i] = As[kk][ty * 4 + i];
      #pragma unroll
      for (int j = 0; j < 4; j++) bb[j] = Bs[kk][tx * 4 + j];
      #pragma unroll
      for (int i = 0; i < 4; i++)
        #pragma unroll
        for (int j = 0; j < 4; j++) acc[i][j] += a[i] * bb[j];
    }
    __syncthreads();
  }
  #pragma unroll
  for (int i = 0; i < 4; i++) {
    int r = bm + ty * 4 + i;
    if (r >= M) continue;
    #pragma unroll
    for (int j = 0; j < 4; j++) {
      int c = bn + tx * 4 + j;
      if (c >= N) continue;
      float v = acc[i][j];
      if (bias)  v += bias[c];
      if (do_relu) v = fmaxf(v, 0.f);
      if (resid) v += resid[(size_t)r * N + c];
      C[(size_t)r * N + c] = v;
    }
  }
}

// ---------------- causal attention, one wave per (b,h,t) ----------------
// q,k,v,o layout: [B*T, H*HD], col = h*HD + hd
__global__ void attn_kernel(const float* __restrict__ q, const float* __restrict__ k,
                            const float* __restrict__ v, float* __restrict__ o) {
  int t = blockIdx.x, h = blockIdx.y, b = blockIdx.z;
  int lane = threadIdx.x;                      // 64 threads = 1 wave
  __shared__ float qv[HD];
  __shared__ float sc[TT];
  size_t base = (size_t)b * TT * HHD + (size_t)h * HD;
  if (lane < HD) qv[lane] = q[base + (size_t)t * HHD + lane];
  __syncthreads();
  const float scale = 0.14907119849998599f;    // 45^-0.5
  float mx = -1e30f;
  for (int s = lane; s <= t; s += 64) {
    const float* kp = k + base + (size_t)s * HHD;
    float d0 = 0.f;
    #pragma unroll
    for (int kk = 0; kk < HD; kk++) d0 += qv[kk] * kp[kk];
    d0 *= scale;
    sc[s] = d0;
    mx = fmaxf(mx, d0);
  }
  #pragma unroll
  for (int off = 32; off; off >>= 1) mx = fmaxf(mx, __shfl_xor(mx, off));
  float sum = 0.f;
  for (int s = lane; s <= t; s += 64) { float e = expf(sc[s] - mx); sc[s] = e; sum += e; }
  #pragma unroll
  for (int off = 32; off; off >>= 1) sum += __shfl_xor(sum, off);
  float inv = 1.0f / sum;
  __syncthreads();                             // sc[] now fully written
  for (int kk = lane; kk < HD; kk += 64) {
    float acc = 0.f;
    for (int s = 0; s <= t; s++) acc += sc[s] * v[base + (size_t)s * HHD + kk];
    o[base + (size_t)t * HHD + kk] = acc * inv;
  }
}

extern "C" void kernel_launch(void* const* d_in, const int* in_sizes, int n_in,
                              void* d_out, int out_size, void* d_ws, size_t ws_size,
                              hipStream_t stream) {
  const int*   idx  = (const int*)  d_in[0];
  const float* tok  = (const float*)d_in[1];
  const float* pos  = (const float*)d_in[2];
  const float* Wq   = (const float*)d_in[3];
  const float* Wk   = (const float*)d_in[4];
  const float* Wv   = (const float*)d_in[5];
  const float* Wp   = (const float*)d_in[6];
  const float* bp   = (const float*)d_in[7];
  const float* g1   = (const float*)d_in[8];
  const float* b1   = (const float*)d_in[9];
  const float* g2   = (const float*)d_in[10];
  const float* b2   = (const float*)d_in[11];
  const float* W1   = (const float*)d_in[12];
  const float* b1f  = (const float*)d_in[13];
  const float* W2   = (const float*)d_in[14];
  const float* b2f  = (const float*)d_in[15];
  const float* gf   = (const float*)d_in[16];
  const float* bf   = (const float*)d_in[17];
  const float* Wlm  = (const float*)d_in[18];
  const float* blm  = (const float*)d_in[19];
  float* out = (float*)d_out;

  // workspace layout (fp32): ~126 MB total
  float* ws = (float*)d_ws;
  size_t off = 0;
  float* x   = ws + off; off += (size_t)MTOK * D;    // residual stream
  float* hb  = ws + off; off += (size_t)MTOK * D;    // LN output
  float* qb  = ws + off; off += (size_t)MTOK * HHD;
  float* kb  = ws + off; off += (size_t)MTOK * HHD;
  float* vb  = ws + off; off += (size_t)MTOK * HHD;
  float* ob  = ws + off; off += (size_t)MTOK * HHD;
  float* ffb = ws + off; off += (size_t)MTOK * FFD;
  float* Bq  = ws + off; off += (size_t)D * HHD;
  float* Bk  = ws + off; off += (size_t)D * HHD;
  float* Bv  = ws + off; off += (size_t)D * HHD;

  embed_kernel<<<MTOK, 256, 0, stream>>>(idx, tok, pos, x);

  const int nrep = (D * HHD + 255) / 256;
  dim3 gqkv((HHD + 63) / 64, (MTOK + 63) / 64);
  dim3 gproj((D + 63) / 64, (MTOK + 63) / 64);
  dim3 gff1((FFD + 63) / 64, (MTOK + 63) / 64);
  dim3 gattn(TT, H, BB);

  for (int l = 0; l < L; l++) {
    ln_kernel<<<MTOK, 256, 0, stream>>>(x, g1 + l * D, b1 + l * D, hb);
    repack_kernel<<<nrep, 256, 0, stream>>>(Wq + (size_t)l * H * D * HD, Bq);
    repack_kernel<<<nrep, 256, 0, stream>>>(Wk + (size_t)l * H * D * HD, Bk);
    repack_kernel<<<nrep, 256, 0, stream>>>(Wv + (size_t)l * H * D * HD, Bv);
    gemm_kernel<<<gqkv, 256, 0, stream>>>(hb, Bq, nullptr, nullptr, qb, MTOK, HHD, D, 0);
    gemm_kernel<<<gqkv, 256, 0, stream>>>(hb, Bk, nullptr, nullptr, kb, MTOK, HHD, D, 0);
    gemm_kernel<<<gqkv, 256, 0, stream>>>(hb, Bv, nullptr, nullptr, vb, MTOK, HHD, D, 0);
    attn_kernel<<<gattn, 64, 0, stream>>>(qb, kb, vb, ob);
    // x = x + o @ Wp + bp   (resid aliases C: each element touched by exactly one thread)
    gemm_kernel<<<gproj, 256, 0, stream>>>(ob, Wp + (size_t)l * HHD * D, bp + l * D, x, x,
                                           MTOK, D, HHD, 0);
    ln_kernel<<<MTOK, 256, 0, stream>>>(x, g2 + l * D, b2 + l * D, hb);
    gemm_kernel<<<gff1, 256, 0, stream>>>(hb, W1 + (size_t)l * D * FFD, b1f + l * FFD, nullptr,
                                          ffb, MTOK, FFD, D, 1);
    gemm_kernel<<<gproj, 256, 0, stream>>>(ffb, W2 + (size_t)l * FFD * D, b2f + l * D, x, x,
                                           MTOK, D, FFD, 0);
  }

  ln_kernel<<<MTOK, 256, 0, stream>>>(x, gf, bf, hb);
  dim3 glm((VV + 63) / 64, (MTOK + 63) / 64);
  gemm_kernel<<<glm, 256, 0, stream>>>(hb, Wlm, blm, nullptr, out, MTOK, VV, D, 0);
}